// Round 7
// baseline (329.485 us; speedup 1.0000x reference)
//
#include <hip/hip_runtime.h>
#include <hip/hip_bf16.h>
#include <math.h>

// Problem constants
#define Bsz 2
#define Nseq 2048
#define Edim 1024
#define HQ 16
#define HK 4
#define Dh 64
#define ROWS (Bsz * Nseq)          // 4096
#define QKVW 1536                  // q(1024) | k(256) | v(256)
#define SCL 0.1803368801111244f    // 0.125 * log2(e)  (softmax in exp2 domain)

typedef __attribute__((ext_vector_type(8))) short short8;
typedef __attribute__((ext_vector_type(4))) float f32x4;

__device__ __forceinline__ ushort f2bf_u(float f) {
    union { __hip_bfloat16 h; ushort u; } c;
    c.h = __float2bfloat16(f);
    return c.u;
}
__device__ __forceinline__ unsigned bfpk(float lo, float hi) {
    return ((unsigned)f2bf_u(hi) << 16) | (unsigned)f2bf_u(lo);
}

// async global->LDS, 16B per lane; lds base must be wave-uniform
__device__ __forceinline__ void gld16(const void* g, void* l) {
    __builtin_amdgcn_global_load_lds(
        (const __attribute__((address_space(1))) unsigned*)g,
        (__attribute__((address_space(3))) unsigned*)l, 16, 0, 0);
}

// ---------------- prep: cast x to bf16 ---------------------------------------
__global__ __launch_bounds__(256) void castx(const float* __restrict__ x,
                                             ushort* __restrict__ xb) {
    size_t i = ((size_t)blockIdx.x * 256 + threadIdx.x) * 8;
    float4 a = *(const float4*)(x + i);
    float4 c = *(const float4*)(x + i + 4);
    short8 v;
    v[0] = f2bf_u(a.x); v[1] = f2bf_u(a.y); v[2] = f2bf_u(a.z); v[3] = f2bf_u(a.w);
    v[4] = f2bf_u(c.x); v[5] = f2bf_u(c.y); v[6] = f2bf_u(c.z); v[7] = f2bf_u(c.w);
    *(short8*)(xb + i) = v;
}

// ---------------- prep: transpose-cast all 4 weights in one launch -----------
// W [1024][N] fp32 -> WT [N][1024] bf16.  2560 tile-blocks of 32x32.
__global__ __launch_bounds__(256) void tcastAll(const float* __restrict__ Wq,
                                                const float* __restrict__ Wk,
                                                const float* __restrict__ Wv,
                                                const float* __restrict__ Wo,
                                                ushort* __restrict__ WqkvT,
                                                ushort* __restrict__ WoT) {
    __shared__ float tle[32][33];
    int bid = blockIdx.x;
    const float* src; ushort* dst; int N;
    if (bid < 1024)      { src = Wq; dst = WqkvT;                          N = 1024; }
    else if (bid < 1280) { src = Wk; dst = WqkvT + (size_t)1024 * 1024;    N = 256;  bid -= 1024; }
    else if (bid < 1536) { src = Wv; dst = WqkvT + (size_t)1280 * 1024;    N = 256;  bid -= 1280; }
    else                 { src = Wo; dst = WoT;                            N = 1024; bid -= 1536; }
    int nj = N >> 5;
    int j0 = (bid % nj) * 32, k0 = (bid / nj) * 32;
    int tx = threadIdx.x & 31, ty = threadIdx.x >> 5;
#pragma unroll
    for (int i = ty; i < 32; i += 8)
        tle[i][tx] = src[(size_t)(k0 + i) * N + j0 + tx];
    __syncthreads();
#pragma unroll
    for (int i = ty; i < 32; i += 8)
        dst[(size_t)(j0 + i) * 1024 + k0 + tx] = f2bf_u(tle[tx][i]);
}

// ---------------- bf16 MFMA GEMM: C[M][N] = A[M][K] @ BT[N][K]^T -------------
// 128x64 tile, BK=32, 4 waves (2x2), global_load_lds staging, dbuf LDS.
// Smaller tile -> 768/512-block grids -> ~3 blocks/CU co-resident (m114 overlap).
template<int WRITE_BF16>
__global__ __launch_bounds__(256) void gemm_bt(const ushort* __restrict__ A,
                                               const ushort* __restrict__ BT,
                                               void* __restrict__ Cout,
                                               int M, int N, int K) {
    __shared__ __attribute__((aligned(16))) ushort As[2][4][128][8];  // 16KB
    __shared__ __attribute__((aligned(16))) ushort Bs[2][4][64][8];   // 8KB
    const int tid = threadIdx.x;
    const int l = tid & 63, li = l & 15, lg = l >> 4;
    const int w = tid >> 6;
    const int wr = w >> 1, wc = w & 1;
    const int row0 = blockIdx.y * 128, col0 = blockIdx.x * 64;

    f32x4 acc[4][2];
#pragma unroll
    for (int i = 0; i < 4; ++i)
#pragma unroll
        for (int j = 0; j < 2; ++j) {
            acc[i][j][0] = 0.f; acc[i][j][1] = 0.f;
            acc[i][j][2] = 0.f; acc[i][j][3] = 0.f;
        }

    const int nk = K >> 5;

#define G_STAGE(buf, kk)                                                        \
    {                                                                           \
        int k0 = (kk) << 5;                                                     \
        _Pragma("unroll")                                                       \
        for (int i = 0; i < 3; ++i) {                                           \
            int id = w + i * 4;                                                 \
            if (id < 8) {                                                       \
                int g = id >> 1, h = id & 1;                                    \
                gld16(A + (size_t)(row0 + h * 64 + l) * K + k0 + g * 8,         \
                      &As[buf][g][h * 64][0]);                                  \
            } else {                                                            \
                int g = id - 8;                                                 \
                gld16(BT + (size_t)(col0 + l) * K + k0 + g * 8,                 \
                      &Bs[buf][g][0][0]);                                       \
            }                                                                   \
        }                                                                       \
    }

    G_STAGE(0, 0);
    __syncthreads();
    int buf = 0;
    for (int kk = 0; kk < nk; ++kk) {
        if (kk + 1 < nk) G_STAGE(buf ^ 1, kk + 1);
        short8 af[4], bfr[2];
#pragma unroll
        for (int mt = 0; mt < 4; ++mt)
            af[mt] = *(const short8*)&As[buf][lg][wr * 64 + mt * 16 + li][0];
#pragma unroll
        for (int nt = 0; nt < 2; ++nt)
            bfr[nt] = *(const short8*)&Bs[buf][lg][wc * 32 + nt * 16 + li][0];
#pragma unroll
        for (int mt = 0; mt < 4; ++mt)
#pragma unroll
            for (int nt = 0; nt < 2; ++nt)
                acc[mt][nt] = __builtin_amdgcn_mfma_f32_16x16x32_bf16(
                    af[mt], bfr[nt], acc[mt][nt], 0, 0, 0);
        __syncthreads();
        buf ^= 1;
    }
#undef G_STAGE

    if (WRITE_BF16) {
        ushort* C = (ushort*)Cout;
#pragma unroll
        for (int mt = 0; mt < 4; ++mt)
#pragma unroll
            for (int r = 0; r < 4; ++r) {
                int rg = row0 + wr * 64 + mt * 16 + lg * 4 + r;
#pragma unroll
                for (int nt = 0; nt < 2; ++nt)
                    C[(size_t)rg * N + col0 + wc * 32 + nt * 16 + li] =
                        f2bf_u(acc[mt][nt][r]);
            }
    } else {
        float* C = (float*)Cout;
#pragma unroll
        for (int mt = 0; mt < 4; ++mt)
#pragma unroll
            for (int r = 0; r < 4; ++r) {
                int rg = row0 + wr * 64 + mt * 16 + lg * 4 + r;
#pragma unroll
                for (int nt = 0; nt < 2; ++nt)
                    C[(size_t)rg * N + col0 + wc * 32 + nt * 16 + li] =
                        acc[mt][nt][r];
            }
    }
}

// ---------------- flash attention: reg-resident Q/K, LDS only for V/P --------
// 4 waves, 64 q-rows/block. Q,K fragments loaded straight from global
// (coalesced 16 rows x 64B per instr). K single-buffered in regs, reloaded
// right after its MFMAs (WAR; softmax+PV covers L2 latency). V reg-staged,
// transposed into dbuf LDS. 24KB LDS -> 3-4 blocks/CU.
__global__ __launch_bounds__(256, 3) void attn_mfma(const ushort* __restrict__ qkv,
                                                    ushort* __restrict__ o) {
    __shared__ __attribute__((aligned(16))) unsigned VtD[2][2048];   // 16KB
    __shared__ __attribute__((aligned(16))) ushort Ps[4][8][16][8];  // 8KB

    const int tid = threadIdx.x;
    const int l = tid & 63, li = l & 15, lg = l >> 4;
    const int w = tid >> 6;
    const int qt = gridDim.x - 1 - blockIdx.x;   // long blocks first
    const int hq = blockIdx.y, b = blockIdx.z, hk = hq >> 2;
    const int r0 = qt * 64;

    // V-stage lane mapping: thread owns keys (kp,kp+1) x 8 d's
    const int kp = 2 * (tid & 31), d0v = (tid >> 5) * 8;
    const int gv = kp >> 3, prv = (kp & 7) >> 1;

    const ushort* qbase = qkv + (size_t)b * Nseq * QKVW;
    const ushort* kbase = qbase + 1024 + hk * 64 + lg * 8;   // + row*QKVW + c*32
    const ushort* vbase = qbase + 1280 + hk * 64 + d0v;      // + row*QKVW

    // Q fragments (persistent)
    short8 q8[2];
#pragma unroll
    for (int c = 0; c < 2; ++c)
        q8[c] = *(const short8*)(qbase + (size_t)(r0 + w * 16 + li) * QKVW +
                                 hq * 64 + (c * 4 + lg) * 8);

    // K(0) fragments
    short8 kf[8];
#pragma unroll
    for (int c = 0; c < 2; ++c)
#pragma unroll
        for (int kb = 0; kb < 4; ++kb)
            kf[c * 4 + kb] =
                *(const short8*)(kbase + (size_t)(kb * 16 + li) * QKVW + c * 32);

    // V(0) -> LDS transposed+swizzled
    {
        short8 va = *(const short8*)(vbase + (size_t)kp * QKVW);
        short8 vb = *(const short8*)(vbase + (size_t)(kp + 1) * QKVW);
#pragma unroll
        for (int i2 = 0; i2 < 8; ++i2) {
            unsigned pv = ((unsigned)(unsigned short)va[i2]) |
                          (((unsigned)(unsigned short)vb[i2]) << 16);
            VtD[0][gv * 256 + (((d0v + i2) * 4 + prv) ^ (gv << 2))] = pv;
        }
    }
    __syncthreads();

    f32x4 oacc[4];
#pragma unroll
    for (int dt = 0; dt < 4; ++dt) {
        oacc[dt][0] = 0.f; oacc[dt][1] = 0.f; oacc[dt][2] = 0.f; oacc[dt][3] = 0.f;
    }
    float m = -INFINITY, lsum = 0.f;
    const int qloc = w * 16 + li;         // this lane's q-row (local to tile)

    for (int t = 0; t <= qt; ++t) {
        const int cur = t & 1, nxt = cur ^ 1;
        const bool pre = (t < qt);
        const int s1 = (t + 1) * 64;

        // issue V(t+1) loads first (regs dead; latency hides under this iter)
        short8 vna, vnb;
        if (pre) {
            vna = *(const short8*)(vbase + (size_t)(s1 + kp) * QKVW);
            vnb = *(const short8*)(vbase + (size_t)(s1 + kp + 1) * QKVW);
        }

        // S^T = K Q  (swapped: lane holds q-row li, keys kb*16+lg*4+r)
        f32x4 s[4];
#pragma unroll
        for (int kb = 0; kb < 4; ++kb) {
            s[kb][0] = 0.f; s[kb][1] = 0.f; s[kb][2] = 0.f; s[kb][3] = 0.f;
        }
#pragma unroll
        for (int c = 0; c < 2; ++c)
#pragma unroll
            for (int kb = 0; kb < 4; ++kb)
                s[kb] = __builtin_amdgcn_mfma_f32_16x16x32_bf16(
                    kf[c * 4 + kb], q8[c], s[kb], 0, 0, 0);

        // reload K for t+1 (WAR on kf keeps this after the MFMAs)
        if (pre) {
#pragma unroll
            for (int c = 0; c < 2; ++c)
#pragma unroll
                for (int kb = 0; kb < 4; ++kb)
                    kf[c * 4 + kb] = *(const short8*)(
                        kbase + (size_t)(s1 + kb * 16 + li) * QKVW + c * 32);
        }

        // scale (exp2 domain) + causal mask
        float p[16];
        const bool last = (t == qt);
#pragma unroll
        for (int kb = 0; kb < 4; ++kb)
#pragma unroll
            for (int r = 0; r < 4; ++r) {
                float sv = s[kb][r] * SCL;
                if (last && (kb * 16 + lg * 4 + r > qloc)) sv = -INFINITY;
                p[kb * 4 + r] = sv;
            }

        // per-lane softmax over own 16 + 2 cross-lg shuffles
        float mx = p[0];
#pragma unroll
        for (int i = 1; i < 16; ++i) mx = fmaxf(mx, p[i]);
        mx = fmaxf(mx, __shfl_xor(mx, 16, 64));
        mx = fmaxf(mx, __shfl_xor(mx, 32, 64));
        float mn = fmaxf(m, mx);
        float al = exp2f(m - mn);         // first tile: exp2(-inf)=0
        float sum = 0.f;
#pragma unroll
        for (int i = 0; i < 16; ++i) {
            float e = exp2f(p[i] - mn);
            p[i] = e;
            sum += e;
        }
        sum += __shfl_xor(sum, 16, 64);
        sum += __shfl_xor(sum, 32, 64);
        m = mn;
        lsum = lsum * al + sum;

        // rescale O: alpha for q-row lg*4+r comes from lane lg*4+r
        float alr[4];
#pragma unroll
        for (int r = 0; r < 4; ++r) alr[r] = __shfl(al, lg * 4 + r, 64);
#pragma unroll
        for (int dt = 0; dt < 4; ++dt)
#pragma unroll
            for (int r = 0; r < 4; ++r) oacc[dt][r] *= alr[r];

        // pack P -> LDS (b64 per kb)
#pragma unroll
        for (int kb = 0; kb < 4; ++kb) {
            unsigned lo = bfpk(p[kb * 4 + 0], p[kb * 4 + 1]);
            unsigned hi = bfpk(p[kb * 4 + 2], p[kb * 4 + 3]);
            *(unsigned long long*)&Ps[w][2 * kb + (lg >> 1)][li][(lg & 1) * 4] =
                ((unsigned long long)hi << 32) | (unsigned long long)lo;
        }

        // write V(t+1) regs -> LDS (vmcnt wait covered by ~full iteration)
        if (pre) {
#pragma unroll
            for (int i2 = 0; i2 < 8; ++i2) {
                unsigned pv = ((unsigned)(unsigned short)vna[i2]) |
                              (((unsigned)(unsigned short)vnb[i2]) << 16);
                VtD[nxt][gv * 256 + (((d0v + i2) * 4 + prv) ^ (gv << 2))] = pv;
            }
        }

        // O += P V  (same-wave P; wave-ordered LDS)
#pragma unroll
        for (int c = 0; c < 2; ++c) {
            short8 pa = *(const short8*)&Ps[w][c * 4 + lg][li][0];
#pragma unroll
            for (int dt = 0; dt < 4; ++dt) {
                int g = c * 4 + lg, d = dt * 16 + li;
                short8 bv = *(const short8*)(&VtD[cur][g * 256 + ((d * 4) ^ (g << 2))]);
                oacc[dt] = __builtin_amdgcn_mfma_f32_16x16x32_bf16(pa, bv, oacc[dt], 0, 0, 0);
            }
        }
        __syncthreads();   // orders Vt dbuf across waves
    }

    // epilogue: 1/l for q-row lg*4+r from lane lg*4+r
    float linv[4];
#pragma unroll
    for (int r = 0; r < 4; ++r) linv[r] = 1.0f / __shfl(lsum, lg * 4 + r, 64);
#pragma unroll
    for (int r = 0; r < 4; ++r) {
        int rg = b * Nseq + r0 + w * 16 + lg * 4 + r;
#pragma unroll
        for (int dt = 0; dt < 4; ++dt)
            o[(size_t)rg * Edim + hq * 64 + dt * 16 + li] =
                f2bf_u(oacc[dt][r] * linv[r]);
    }
}

// ---------------- launch ------------------------------------------------------
extern "C" void kernel_launch(void* const* d_in, const int* in_sizes, int n_in,
                              void* d_out, int out_size, void* d_ws, size_t ws_size,
                              hipStream_t stream) {
    const float* x  = (const float*)d_in[0];
    const float* Wq = (const float*)d_in[1];
    const float* Wk = (const float*)d_in[2];
    const float* Wv = (const float*)d_in[3];
    const float* Wo = (const float*)d_in[4];

    ushort* ws    = (ushort*)d_ws;
    ushort* xb    = ws;                          // 4096x1024
    ushort* WqkvT = xb + (size_t)ROWS * Edim;    // 1536x1024 (rows: WqT|WkT|WvT)
    ushort* WoT   = WqkvT + (size_t)QKVW * Edim; // 1024x1024
    ushort* qkv   = WoT + (size_t)Edim * Edim;   // 4096x1536 bf16
    ushort* at    = qkv + (size_t)ROWS * QKVW;   // 4096x1024 bf16

    castx<<<ROWS * Edim / (256 * 8), 256, 0, stream>>>(x, xb);
    tcastAll<<<2560, 256, 0, stream>>>(Wq, Wk, Wv, Wo, WqkvT, WoT);

    gemm_bt<1><<<dim3(QKVW / 64, ROWS / 128), 256, 0, stream>>>(
        xb, WqkvT, qkv, ROWS, QKVW, Edim);

    attn_mfma<<<dim3(Nseq / 64, HQ, Bsz), 256, 0, stream>>>(qkv, at);

    gemm_bt<0><<<dim3(Edim / 64, ROWS / 128), 256, 0, stream>>>(
        at, WoT, d_out, ROWS, Edim, Edim);
}

// Round 8
// 211.233 us; speedup vs baseline: 1.5598x; 1.5598x over previous
//
#include <hip/hip_runtime.h>
#include <hip/hip_bf16.h>
#include <math.h>

// Problem constants
#define Bsz 2
#define Nseq 2048
#define Edim 1024
#define HQ 16
#define HK 4
#define Dh 64
#define ROWS (Bsz * Nseq)          // 4096
#define QKVW 1536                  // q(1024) | k(256) | v(256)
#define SCL 0.1803368801111244f    // 0.125 * log2(e)  (softmax in exp2 domain)

typedef __attribute__((ext_vector_type(8))) short short8;
typedef __attribute__((ext_vector_type(4))) float f32x4;

__device__ __forceinline__ ushort f2bf_u(float f) {
    union { __hip_bfloat16 h; ushort u; } c;
    c.h = __float2bfloat16(f);
    return c.u;
}
__device__ __forceinline__ unsigned bfpk(float lo, float hi) {
    return ((unsigned)f2bf_u(hi) << 16) | (unsigned)f2bf_u(lo);
}

// async global->LDS, 16B per lane; lds base must be wave-uniform
__device__ __forceinline__ void gld16(const void* g, void* l) {
    __builtin_amdgcn_global_load_lds(
        (const __attribute__((address_space(1))) unsigned*)g,
        (__attribute__((address_space(3))) unsigned*)l, 16, 0, 0);
}

// ---------------- prep: cast x to bf16 ---------------------------------------
__global__ __launch_bounds__(256) void castx(const float* __restrict__ x,
                                             ushort* __restrict__ xb) {
    size_t i = ((size_t)blockIdx.x * 256 + threadIdx.x) * 8;
    float4 a = *(const float4*)(x + i);
    float4 c = *(const float4*)(x + i + 4);
    short8 v;
    v[0] = f2bf_u(a.x); v[1] = f2bf_u(a.y); v[2] = f2bf_u(a.z); v[3] = f2bf_u(a.w);
    v[4] = f2bf_u(c.x); v[5] = f2bf_u(c.y); v[6] = f2bf_u(c.z); v[7] = f2bf_u(c.w);
    *(short8*)(xb + i) = v;
}

// ---------------- prep: transpose-cast all 4 weights in one launch -----------
// W [1024][N] fp32 -> WT [N][1024] bf16.  2560 tile-blocks of 32x32.
__global__ __launch_bounds__(256) void tcastAll(const float* __restrict__ Wq,
                                                const float* __restrict__ Wk,
                                                const float* __restrict__ Wv,
                                                const float* __restrict__ Wo,
                                                ushort* __restrict__ WqkvT,
                                                ushort* __restrict__ WoT) {
    __shared__ float tle[32][33];
    int bid = blockIdx.x;
    const float* src; ushort* dst; int N;
    if (bid < 1024)      { src = Wq; dst = WqkvT;                          N = 1024; }
    else if (bid < 1280) { src = Wk; dst = WqkvT + (size_t)1024 * 1024;    N = 256;  bid -= 1024; }
    else if (bid < 1536) { src = Wv; dst = WqkvT + (size_t)1280 * 1024;    N = 256;  bid -= 1280; }
    else                 { src = Wo; dst = WoT;                            N = 1024; bid -= 1536; }
    int nj = N >> 5;
    int j0 = (bid % nj) * 32, k0 = (bid / nj) * 32;
    int tx = threadIdx.x & 31, ty = threadIdx.x >> 5;
#pragma unroll
    for (int i = ty; i < 32; i += 8)
        tle[i][tx] = src[(size_t)(k0 + i) * N + j0 + tx];
    __syncthreads();
#pragma unroll
    for (int i = ty; i < 32; i += 8)
        dst[(size_t)(j0 + i) * 1024 + k0 + tx] = f2bf_u(tle[tx][i]);
}

// ---------------- bf16 MFMA GEMM: C[M][N] = A[M][K] @ BT[N][K]^T -------------
// 128x64 tile, BK=32, 4 waves (2x2), global_load_lds staging, dbuf LDS.
template<int WRITE_BF16>
__global__ __launch_bounds__(256) void gemm_bt(const ushort* __restrict__ A,
                                               const ushort* __restrict__ BT,
                                               void* __restrict__ Cout,
                                               int M, int N, int K) {
    __shared__ __attribute__((aligned(16))) ushort As[2][4][128][8];  // 16KB
    __shared__ __attribute__((aligned(16))) ushort Bs[2][4][64][8];   // 8KB
    const int tid = threadIdx.x;
    const int l = tid & 63, li = l & 15, lg = l >> 4;
    const int w = tid >> 6;
    const int wr = w >> 1, wc = w & 1;
    const int row0 = blockIdx.y * 128, col0 = blockIdx.x * 64;

    f32x4 acc[4][2];
#pragma unroll
    for (int i = 0; i < 4; ++i)
#pragma unroll
        for (int j = 0; j < 2; ++j) {
            acc[i][j][0] = 0.f; acc[i][j][1] = 0.f;
            acc[i][j][2] = 0.f; acc[i][j][3] = 0.f;
        }

    const int nk = K >> 5;

#define G_STAGE(buf, kk)                                                        \
    {                                                                           \
        int k0 = (kk) << 5;                                                     \
        _Pragma("unroll")                                                       \
        for (int i = 0; i < 3; ++i) {                                           \
            int id = w + i * 4;                                                 \
            if (id < 8) {                                                       \
                int g = id >> 1, h = id & 1;                                    \
                gld16(A + (size_t)(row0 + h * 64 + l) * K + k0 + g * 8,         \
                      &As[buf][g][h * 64][0]);                                  \
            } else {                                                            \
                int g = id - 8;                                                 \
                gld16(BT + (size_t)(col0 + l) * K + k0 + g * 8,                 \
                      &Bs[buf][g][0][0]);                                       \
            }                                                                   \
        }                                                                       \
    }

    G_STAGE(0, 0);
    __syncthreads();
    int buf = 0;
    for (int kk = 0; kk < nk; ++kk) {
        if (kk + 1 < nk) G_STAGE(buf ^ 1, kk + 1);
        short8 af[4], bfr[2];
#pragma unroll
        for (int mt = 0; mt < 4; ++mt)
            af[mt] = *(const short8*)&As[buf][lg][wr * 64 + mt * 16 + li][0];
#pragma unroll
        for (int nt = 0; nt < 2; ++nt)
            bfr[nt] = *(const short8*)&Bs[buf][lg][wc * 32 + nt * 16 + li][0];
#pragma unroll
        for (int mt = 0; mt < 4; ++mt)
#pragma unroll
            for (int nt = 0; nt < 2; ++nt)
                acc[mt][nt] = __builtin_amdgcn_mfma_f32_16x16x32_bf16(
                    af[mt], bfr[nt], acc[mt][nt], 0, 0, 0);
        __syncthreads();
        buf ^= 1;
    }
#undef G_STAGE

    if (WRITE_BF16) {
        ushort* C = (ushort*)Cout;
#pragma unroll
        for (int mt = 0; mt < 4; ++mt)
#pragma unroll
            for (int r = 0; r < 4; ++r) {
                int rg = row0 + wr * 64 + mt * 16 + lg * 4 + r;
#pragma unroll
                for (int nt = 0; nt < 2; ++nt)
                    C[(size_t)rg * N + col0 + wc * 32 + nt * 16 + li] =
                        f2bf_u(acc[mt][nt][r]);
            }
    } else {
        float* C = (float*)Cout;
#pragma unroll
        for (int mt = 0; mt < 4; ++mt)
#pragma unroll
            for (int r = 0; r < 4; ++r) {
                int rg = row0 + wr * 64 + mt * 16 + lg * 4 + r;
#pragma unroll
                for (int nt = 0; nt < 2; ++nt)
                    C[(size_t)rg * N + col0 + wc * 32 + nt * 16 + li] =
                        acc[mt][nt][r];
            }
    }
}

// ---------------- flash attention, 2-phase pipelined, balanced pairing -------
// Each block handles q-tiles {bx, 31-bx}: (bx+1)+(32-bx)=33 key-tiles — uniform.
// Grid (16,16,2)=512 blocks, 2/CU steady, no ragged tail.
// Round-6 staging: K via gld16 dbuf, V reg-staged dbuf, Q per-lane registers.
__global__ __launch_bounds__(256) void attn_mfma(const ushort* __restrict__ qkv,
                                                 ushort* __restrict__ o) {
    __shared__ __attribute__((aligned(16))) char smem[40960];
    ushort (*Ks)[8][64][8] = (ushort (*)[8][64][8])smem;          // 2 x 8KB
    unsigned (*VtD)[2048]  = (unsigned (*)[2048])(smem + 16384);  // 2 x 8KB
    ushort (*Ps)[8][16][8] = (ushort (*)[8][16][8])(smem + 32768);// 8KB

    const int tid = threadIdx.x;
    const int l = tid & 63, li = l & 15, lg = l >> 4;
    const int w = tid >> 6;
    const int bx = blockIdx.x;                   // 0..15
    const int hq = blockIdx.y, b = blockIdx.z, hk = hq >> 2;

    // V-stage lane mapping: thread owns keys (kp,kp+1) x 8 d's
    const int kp = 2 * (tid & 31), d0v = (tid >> 5) * 8;
    const int gv = kp >> 3, prv = (kp & 7) >> 1;

    const ushort* base  = qkv + (size_t)b * Nseq * QKVW;
    const ushort* vbase = base + 1280 + hk * 64 + d0v;     // + row*QKVW
    const int qloc = w * 16 + li;                          // lane's q-row in tile

    for (int hseg = 0; hseg < 2; ++hseg) {
        const int qt = hseg ? (31 - bx) : bx;
        const int r0 = qt * 64;

        // Q fragments per-lane (one-time; latency amortized over whole half)
        short8 q8[2];
#pragma unroll
        for (int c = 0; c < 2; ++c)
            q8[c] = *(const short8*)(base + (size_t)(r0 + qloc) * QKVW +
                                     hq * 64 + (c * 4 + lg) * 8);

        // prologue: stage K(0) via gld16, V(0) via regs
#pragma unroll
        for (int i = 0; i < 2; ++i) {
            int g = w + i * 4;
            gld16(base + (size_t)l * QKVW + 1024 + hk * 64 + g * 8,
                  &Ks[0][g][0][0]);
        }
        short8 va = *(const short8*)(vbase + (size_t)kp * QKVW);
        short8 vb = *(const short8*)(vbase + (size_t)(kp + 1) * QKVW);
        __syncthreads();                  // K(0) in LDS; V(0) regs complete
#pragma unroll
        for (int i2 = 0; i2 < 8; ++i2) {
            unsigned pv = ((unsigned)(unsigned short)va[i2]) |
                          (((unsigned)(unsigned short)vb[i2]) << 16);
            VtD[0][gv * 256 + (((d0v + i2) * 4 + prv) ^ (gv << 2))] = pv;
        }
        __syncthreads();                  // V(0) visible

        f32x4 oacc[4];
#pragma unroll
        for (int dt = 0; dt < 4; ++dt) {
            oacc[dt][0] = 0.f; oacc[dt][1] = 0.f;
            oacc[dt][2] = 0.f; oacc[dt][3] = 0.f;
        }
        float m = -INFINITY, lsum = 0.f;

        for (int t = 0; t <= qt; ++t) {
            const int cur = t & 1, nxt = cur ^ 1;
            const bool pre = (t < qt);
            short8 vna, vnb;
            if (pre) {                    // issue next tile's loads FIRST
                const int s1 = (t + 1) * 64;
#pragma unroll
                for (int i = 0; i < 2; ++i) {
                    int g = w + i * 4;
                    gld16(base + (size_t)(s1 + l) * QKVW + 1024 + hk * 64 + g * 8,
                          &Ks[nxt][g][0][0]);
                }
                const ushort* vr = vbase + (size_t)(s1 + kp) * QKVW;
                vna = *(const short8*)vr;
                vnb = *(const short8*)(vr + QKVW);
            }

            // S^T = K Q  (swapped: lane holds q-row li, keys kb*16+lg*4+r)
            f32x4 s[4];
#pragma unroll
            for (int kb = 0; kb < 4; ++kb) {
                s[kb][0] = 0.f; s[kb][1] = 0.f; s[kb][2] = 0.f; s[kb][3] = 0.f;
            }
#pragma unroll
            for (int c = 0; c < 2; ++c)
#pragma unroll
                for (int kb = 0; kb < 4; ++kb) {
                    short8 bk = *(const short8*)&Ks[cur][c * 4 + lg][kb * 16 + li][0];
                    s[kb] = __builtin_amdgcn_mfma_f32_16x16x32_bf16(bk, q8[c], s[kb], 0, 0, 0);
                }

            // scale (exp2 domain) + causal mask
            float p[16];
            const bool last = (t == qt);
#pragma unroll
            for (int kb = 0; kb < 4; ++kb)
#pragma unroll
                for (int r = 0; r < 4; ++r) {
                    float sv = s[kb][r] * SCL;
                    if (last && (kb * 16 + lg * 4 + r > qloc)) sv = -INFINITY;
                    p[kb * 4 + r] = sv;
                }

            // per-lane softmax over own 16 + 2 cross-lg shuffles
            float mx = p[0];
#pragma unroll
            for (int i = 1; i < 16; ++i) mx = fmaxf(mx, p[i]);
            mx = fmaxf(mx, __shfl_xor(mx, 16, 64));
            mx = fmaxf(mx, __shfl_xor(mx, 32, 64));
            float mn = fmaxf(m, mx);
            float al = exp2f(m - mn);     // first tile: exp2(-inf)=0
            float sum = 0.f;
#pragma unroll
            for (int i = 0; i < 16; ++i) {
                float e = exp2f(p[i] - mn);
                p[i] = e;
                sum += e;
            }
            sum += __shfl_xor(sum, 16, 64);
            sum += __shfl_xor(sum, 32, 64);
            m = mn;
            lsum = lsum * al + sum;

            // rescale O: alpha for q-row lg*4+r comes from lane lg*4+r
            float alr[4];
#pragma unroll
            for (int r = 0; r < 4; ++r) alr[r] = __shfl(al, lg * 4 + r, 64);
#pragma unroll
            for (int dt = 0; dt < 4; ++dt)
#pragma unroll
                for (int r = 0; r < 4; ++r) oacc[dt][r] *= alr[r];

            // pack P -> LDS (b64 per kb)
#pragma unroll
            for (int kb = 0; kb < 4; ++kb) {
                unsigned lo = bfpk(p[kb * 4 + 0], p[kb * 4 + 1]);
                unsigned hi = bfpk(p[kb * 4 + 2], p[kb * 4 + 3]);
                *(unsigned long long*)&Ps[w][2 * kb + (lg >> 1)][li][(lg & 1) * 4] =
                    ((unsigned long long)hi << 32) | (unsigned long long)lo;
            }

            // write V(t+1) regs -> LDS (overlapped with softmax above)
            if (pre) {
#pragma unroll
                for (int i2 = 0; i2 < 8; ++i2) {
                    unsigned pv = ((unsigned)(unsigned short)vna[i2]) |
                                  (((unsigned)(unsigned short)vnb[i2]) << 16);
                    VtD[nxt][gv * 256 + (((d0v + i2) * 4 + prv) ^ (gv << 2))] = pv;
                }
            }

            // O += P V  (same-wave P; wave-ordered LDS)
#pragma unroll
            for (int c = 0; c < 2; ++c) {
                short8 pa = *(const short8*)&Ps[w][c * 4 + lg][li][0];
#pragma unroll
                for (int dt = 0; dt < 4; ++dt) {
                    int g = c * 4 + lg, d = dt * 16 + li;
                    short8 bv = *(const short8*)(&VtD[cur][g * 256 + ((d * 4) ^ (g << 2))]);
                    oacc[dt] = __builtin_amdgcn_mfma_f32_16x16x32_bf16(pa, bv, oacc[dt], 0, 0, 0);
                }
            }
            __syncthreads();   // drains K(t+1) gld16 + V writes; cur reads done
        }

        // epilogue: 1/l for q-row lg*4+r from lane lg*4+r
        float linv[4];
#pragma unroll
        for (int r = 0; r < 4; ++r) linv[r] = 1.0f / __shfl(lsum, lg * 4 + r, 64);
#pragma unroll
        for (int r = 0; r < 4; ++r) {
            int rg = b * Nseq + r0 + w * 16 + lg * 4 + r;
#pragma unroll
            for (int dt = 0; dt < 4; ++dt)
                o[(size_t)rg * Edim + hq * 64 + dt * 16 + li] =
                    f2bf_u(oacc[dt][r] * linv[r]);
        }
        // loop's final __syncthreads ordered all LDS reads before next half
    }
}

// ---------------- launch ------------------------------------------------------
extern "C" void kernel_launch(void* const* d_in, const int* in_sizes, int n_in,
                              void* d_out, int out_size, void* d_ws, size_t ws_size,
                              hipStream_t stream) {
    const float* x  = (const float*)d_in[0];
    const float* Wq = (const float*)d_in[1];
    const float* Wk = (const float*)d_in[2];
    const float* Wv = (const float*)d_in[3];
    const float* Wo = (const float*)d_in[4];

    ushort* ws    = (ushort*)d_ws;
    ushort* xb    = ws;                          // 4096x1024
    ushort* WqkvT = xb + (size_t)ROWS * Edim;    // 1536x1024 (rows: WqT|WkT|WvT)
    ushort* WoT   = WqkvT + (size_t)QKVW * Edim; // 1024x1024
    ushort* qkv   = WoT + (size_t)Edim * Edim;   // 4096x1536 bf16
    ushort* at    = qkv + (size_t)ROWS * QKVW;   // 4096x1024 bf16

    castx<<<ROWS * Edim / (256 * 8), 256, 0, stream>>>(x, xb);
    tcastAll<<<2560, 256, 0, stream>>>(Wq, Wk, Wv, Wo, WqkvT, WoT);

    gemm_bt<1><<<dim3(QKVW / 64, ROWS / 128), 256, 0, stream>>>(
        xb, WqkvT, qkv, ROWS, QKVW, Edim);

    attn_mfma<<<dim3(Nseq / 128, HQ, Bsz), 256, 0, stream>>>(qkv, at);

    gemm_bt<0><<<dim3(Edim / 64, ROWS / 128), 256, 0, stream>>>(
        at, WoT, d_out, ROWS, Edim, Edim);
}

// Round 9
// 209.337 us; speedup vs baseline: 1.5739x; 1.0091x over previous
//
#include <hip/hip_runtime.h>
#include <hip/hip_bf16.h>
#include <math.h>

// Problem constants
#define Bsz 2
#define Nseq 2048
#define Edim 1024
#define HQ 16
#define HK 4
#define Dh 64
#define ROWS (Bsz * Nseq)          // 4096
#define QKVW 1536                  // q(1024) | k(256) | v(256)
#define SCL 0.1803368801111244f    // 0.125 * log2(e)  (folded into Wq at tcast)

typedef __attribute__((ext_vector_type(8))) short short8;
typedef __attribute__((ext_vector_type(4))) float f32x4;

union S8U { short8 s8; unsigned u[4]; };

__device__ __forceinline__ ushort f2bf_u(float f) {
    union { __hip_bfloat16 h; ushort u; } c;
    c.h = __float2bfloat16(f);
    return c.u;
}
__device__ __forceinline__ unsigned bfpk(float lo, float hi) {
    return ((unsigned)f2bf_u(hi) << 16) | (unsigned)f2bf_u(lo);
}

// async global->LDS, 16B per lane; lds base must be wave-uniform
__device__ __forceinline__ void gld16(const void* g, void* l) {
    __builtin_amdgcn_global_load_lds(
        (const __attribute__((address_space(1))) unsigned*)g,
        (__attribute__((address_space(3))) unsigned*)l, 16, 0, 0);
}

// ---------------- prep: cast x to bf16 ---------------------------------------
__global__ __launch_bounds__(256) void castx(const float* __restrict__ x,
                                             ushort* __restrict__ xb) {
    size_t i = ((size_t)blockIdx.x * 256 + threadIdx.x) * 8;
    float4 a = *(const float4*)(x + i);
    float4 c = *(const float4*)(x + i + 4);
    short8 v;
    v[0] = f2bf_u(a.x); v[1] = f2bf_u(a.y); v[2] = f2bf_u(a.z); v[3] = f2bf_u(a.w);
    v[4] = f2bf_u(c.x); v[5] = f2bf_u(c.y); v[6] = f2bf_u(c.z); v[7] = f2bf_u(c.w);
    *(short8*)(xb + i) = v;
}

// ---------------- prep: transpose-cast all 4 weights in one launch -----------
// W [1024][N] fp32 -> WT [N][1024] bf16.  Wq pre-scaled by SCL (softmax fold).
__global__ __launch_bounds__(256) void tcastAll(const float* __restrict__ Wq,
                                                const float* __restrict__ Wk,
                                                const float* __restrict__ Wv,
                                                const float* __restrict__ Wo,
                                                ushort* __restrict__ WqkvT,
                                                ushort* __restrict__ WoT) {
    __shared__ float tle[32][33];
    int bid = blockIdx.x;
    const float* src; ushort* dst; int N; float sc = 1.0f;
    if (bid < 1024)      { src = Wq; dst = WqkvT;                          N = 1024; sc = SCL; }
    else if (bid < 1280) { src = Wk; dst = WqkvT + (size_t)1024 * 1024;    N = 256;  bid -= 1024; }
    else if (bid < 1536) { src = Wv; dst = WqkvT + (size_t)1280 * 1024;    N = 256;  bid -= 1280; }
    else                 { src = Wo; dst = WoT;                            N = 1024; bid -= 1536; }
    int nj = N >> 5;
    int j0 = (bid % nj) * 32, k0 = (bid / nj) * 32;
    int tx = threadIdx.x & 31, ty = threadIdx.x >> 5;
#pragma unroll
    for (int i = ty; i < 32; i += 8)
        tle[i][tx] = src[(size_t)(k0 + i) * N + j0 + tx];
    __syncthreads();
#pragma unroll
    for (int i = ty; i < 32; i += 8)
        dst[(size_t)(j0 + i) * 1024 + k0 + tx] = f2bf_u(tle[tx][i] * sc);
}

// ---------------- bf16 MFMA GEMM: C[M][N] = A[M][K] @ BT[N][K]^T -------------
// 128x64 tile, BK=32, 4 waves (2x2), global_load_lds staging, dbuf LDS.
template<int WRITE_BF16>
__global__ __launch_bounds__(256) void gemm_bt(const ushort* __restrict__ A,
                                               const ushort* __restrict__ BT,
                                               void* __restrict__ Cout,
                                               int M, int N, int K) {
    __shared__ __attribute__((aligned(16))) ushort As[2][4][128][8];  // 16KB
    __shared__ __attribute__((aligned(16))) ushort Bs[2][4][64][8];   // 8KB
    const int tid = threadIdx.x;
    const int l = tid & 63, li = l & 15, lg = l >> 4;
    const int w = tid >> 6;
    const int wr = w >> 1, wc = w & 1;
    const int row0 = blockIdx.y * 128, col0 = blockIdx.x * 64;

    f32x4 acc[4][2];
#pragma unroll
    for (int i = 0; i < 4; ++i)
#pragma unroll
        for (int j = 0; j < 2; ++j) {
            acc[i][j][0] = 0.f; acc[i][j][1] = 0.f;
            acc[i][j][2] = 0.f; acc[i][j][3] = 0.f;
        }

    const int nk = K >> 5;

#define G_STAGE(buf, kk)                                                        \
    {                                                                           \
        int k0 = (kk) << 5;                                                     \
        _Pragma("unroll")                                                       \
        for (int i = 0; i < 3; ++i) {                                           \
            int id = w + i * 4;                                                 \
            if (id < 8) {                                                       \
                int g = id >> 1, h = id & 1;                                    \
                gld16(A + (size_t)(row0 + h * 64 + l) * K + k0 + g * 8,         \
                      &As[buf][g][h * 64][0]);                                  \
            } else {                                                            \
                int g = id - 8;                                                 \
                gld16(BT + (size_t)(col0 + l) * K + k0 + g * 8,                 \
                      &Bs[buf][g][0][0]);                                       \
            }                                                                   \
        }                                                                       \
    }

    G_STAGE(0, 0);
    __syncthreads();
    int buf = 0;
    for (int kk = 0; kk < nk; ++kk) {
        if (kk + 1 < nk) G_STAGE(buf ^ 1, kk + 1);
        short8 af[4], bfr[2];
#pragma unroll
        for (int mt = 0; mt < 4; ++mt)
            af[mt] = *(const short8*)&As[buf][lg][wr * 64 + mt * 16 + li][0];
#pragma unroll
        for (int nt = 0; nt < 2; ++nt)
            bfr[nt] = *(const short8*)&Bs[buf][lg][wc * 32 + nt * 16 + li][0];
#pragma unroll
        for (int mt = 0; mt < 4; ++mt)
#pragma unroll
            for (int nt = 0; nt < 2; ++nt)
                acc[mt][nt] = __builtin_amdgcn_mfma_f32_16x16x32_bf16(
                    af[mt], bfr[nt], acc[mt][nt], 0, 0, 0);
        __syncthreads();
        buf ^= 1;
    }
#undef G_STAGE

    if (WRITE_BF16) {
        ushort* C = (ushort*)Cout;
#pragma unroll
        for (int mt = 0; mt < 4; ++mt)
#pragma unroll
            for (int r = 0; r < 4; ++r) {
                int rg = row0 + wr * 64 + mt * 16 + lg * 4 + r;
#pragma unroll
                for (int nt = 0; nt < 2; ++nt)
                    C[(size_t)rg * N + col0 + wc * 32 + nt * 16 + li] =
                        f2bf_u(acc[mt][nt][r]);
            }
    } else {
        float* C = (float*)Cout;
#pragma unroll
        for (int mt = 0; mt < 4; ++mt)
#pragma unroll
            for (int r = 0; r < 4; ++r) {
                int rg = row0 + wr * 64 + mt * 16 + lg * 4 + r;
#pragma unroll
                for (int nt = 0; nt < 2; ++nt)
                    C[(size_t)rg * N + col0 + wc * 32 + nt * 16 + li] =
                        acc[mt][nt][r];
            }
    }
}

// ---------------- flash attention, 2-phase pipelined, balanced pairing -------
// Each block handles q-tiles {bx, 31-bx}: 33 key-tiles total — uniform.
// Q pre-scaled (SCL folded into Wq). Defer-max (THR=8, exact). V-pack via
// v_perm_b32. K via gld16 dbuf, V reg-staged dbuf.
__global__ __launch_bounds__(256) void attn_mfma(const ushort* __restrict__ qkv,
                                                 ushort* __restrict__ o) {
    __shared__ __attribute__((aligned(16))) char smem[40960];
    ushort (*Ks)[8][64][8] = (ushort (*)[8][64][8])smem;          // 2 x 8KB
    unsigned (*VtD)[2048]  = (unsigned (*)[2048])(smem + 16384);  // 2 x 8KB
    ushort (*Ps)[8][16][8] = (ushort (*)[8][16][8])(smem + 32768);// 8KB

    const int tid = threadIdx.x;
    const int l = tid & 63, li = l & 15, lg = l >> 4;
    const int w = tid >> 6;
    const int bx = blockIdx.x;                   // 0..15
    const int hq = blockIdx.y, b = blockIdx.z, hk = hq >> 2;

    // V-stage lane mapping: thread owns keys (kp,kp+1) x 8 d's
    const int kp = 2 * (tid & 31), d0v = (tid >> 5) * 8;
    const int gv = kp >> 3, prv = (kp & 7) >> 1;

    const ushort* base  = qkv + (size_t)b * Nseq * QKVW;
    const ushort* vbase = base + 1280 + hk * 64 + d0v;     // + row*QKVW
    const int qloc = w * 16 + li;                          // lane's q-row in tile

    for (int hseg = 0; hseg < 2; ++hseg) {
        const int qt = hseg ? (31 - bx) : bx;
        const int r0 = qt * 64;

        // Q fragments per-lane (pre-scaled by SCL via Wq)
        short8 q8[2];
#pragma unroll
        for (int c = 0; c < 2; ++c)
            q8[c] = *(const short8*)(base + (size_t)(r0 + qloc) * QKVW +
                                     hq * 64 + (c * 4 + lg) * 8);

        // prologue: stage K(0) via gld16, V(0) via regs
#pragma unroll
        for (int i = 0; i < 2; ++i) {
            int g = w + i * 4;
            gld16(base + (size_t)l * QKVW + 1024 + hk * 64 + g * 8,
                  &Ks[0][g][0][0]);
        }
        short8 va = *(const short8*)(vbase + (size_t)kp * QKVW);
        short8 vb = *(const short8*)(vbase + (size_t)(kp + 1) * QKVW);
        __syncthreads();                  // K(0) in LDS; V(0) regs complete
        {
            S8U ua, ub; ua.s8 = va; ub.s8 = vb;
#pragma unroll
            for (int j = 0; j < 4; ++j) {
                VtD[0][gv * 256 + (((d0v + 2 * j) * 4 + prv) ^ (gv << 2))] =
                    __builtin_amdgcn_perm(ub.u[j], ua.u[j], 0x05040100u);
                VtD[0][gv * 256 + (((d0v + 2 * j + 1) * 4 + prv) ^ (gv << 2))] =
                    __builtin_amdgcn_perm(ub.u[j], ua.u[j], 0x07060302u);
            }
        }
        __syncthreads();                  // V(0) visible

        f32x4 oacc[4];
#pragma unroll
        for (int dt = 0; dt < 4; ++dt) {
            oacc[dt][0] = 0.f; oacc[dt][1] = 0.f;
            oacc[dt][2] = 0.f; oacc[dt][3] = 0.f;
        }
        float m = -INFINITY, lsum = 0.f;

        for (int t = 0; t <= qt; ++t) {
            const int cur = t & 1, nxt = cur ^ 1;
            const bool pre = (t < qt);
            short8 vna, vnb;
            if (pre) {                    // issue next tile's loads FIRST
                const int s1 = (t + 1) * 64;
#pragma unroll
                for (int i = 0; i < 2; ++i) {
                    int g = w + i * 4;
                    gld16(base + (size_t)(s1 + l) * QKVW + 1024 + hk * 64 + g * 8,
                          &Ks[nxt][g][0][0]);
                }
                const ushort* vr = vbase + (size_t)(s1 + kp) * QKVW;
                vna = *(const short8*)vr;
                vnb = *(const short8*)(vr + QKVW);
            }

            // S^T = K Q  (swapped: lane holds q-row li, keys kb*16+lg*4+r)
            f32x4 s[4];
#pragma unroll
            for (int kb = 0; kb < 4; ++kb) {
                s[kb][0] = 0.f; s[kb][1] = 0.f; s[kb][2] = 0.f; s[kb][3] = 0.f;
            }
#pragma unroll
            for (int c = 0; c < 2; ++c)
#pragma unroll
                for (int kb = 0; kb < 4; ++kb) {
                    short8 bk = *(const short8*)&Ks[cur][c * 4 + lg][kb * 16 + li][0];
                    s[kb] = __builtin_amdgcn_mfma_f32_16x16x32_bf16(bk, q8[c], s[kb], 0, 0, 0);
                }

            // causal mask (uniform branch; only diagonal tile partial)
            float p[16];
            const bool last = (t == qt);
#pragma unroll
            for (int kb = 0; kb < 4; ++kb)
#pragma unroll
                for (int r = 0; r < 4; ++r) {
                    float sv = s[kb][r];
                    if (last && (kb * 16 + lg * 4 + r > qloc)) sv = -INFINITY;
                    p[kb * 4 + r] = sv;
                }

            // row max via max3 tree + 2 cross-lg shuffles
            float mx = fmaxf(fmaxf(
                fmaxf(fmaxf(p[0], p[1]), fmaxf(p[2], p[3])),
                fmaxf(fmaxf(p[4], p[5]), fmaxf(p[6], p[7]))),
                fmaxf(fmaxf(fmaxf(p[8], p[9]), fmaxf(p[10], p[11])),
                      fmaxf(fmaxf(p[12], p[13]), fmaxf(p[14], p[15]))));
            mx = fmaxf(mx, __shfl_xor(mx, 16, 64));
            mx = fmaxf(mx, __shfl_xor(mx, 32, 64));

            // defer-max: only update offset/rescale when growth > 8 (exact math)
            if (__any(mx - m > 8.0f)) {
                float mn = fmaxf(m, mx);
                float al = exp2f(m - mn);   // first tile: exp2(-inf)=0
                m = mn;
                lsum *= al;
                float alr[4];
#pragma unroll
                for (int r = 0; r < 4; ++r) alr[r] = __shfl(al, lg * 4 + r, 64);
#pragma unroll
                for (int dt = 0; dt < 4; ++dt)
#pragma unroll
                    for (int r = 0; r < 4; ++r) oacc[dt][r] *= alr[r];
            }

            float sum = 0.f;
#pragma unroll
            for (int i = 0; i < 16; ++i) {
                float e = exp2f(p[i] - m);
                p[i] = e;
                sum += e;
            }
            sum += __shfl_xor(sum, 16, 64);
            sum += __shfl_xor(sum, 32, 64);
            lsum += sum;

            // pack P -> LDS (b64 per kb)
#pragma unroll
            for (int kb = 0; kb < 4; ++kb) {
                unsigned lo = bfpk(p[kb * 4 + 0], p[kb * 4 + 1]);
                unsigned hi = bfpk(p[kb * 4 + 2], p[kb * 4 + 3]);
                *(unsigned long long*)&Ps[w][2 * kb + (lg >> 1)][li][(lg & 1) * 4] =
                    ((unsigned long long)hi << 32) | (unsigned long long)lo;
            }

            // write V(t+1) regs -> LDS (overlapped with softmax above)
            if (pre) {
                S8U ua, ub; ua.s8 = vna; ub.s8 = vnb;
#pragma unroll
                for (int j = 0; j < 4; ++j) {
                    VtD[nxt][gv * 256 + (((d0v + 2 * j) * 4 + prv) ^ (gv << 2))] =
                        __builtin_amdgcn_perm(ub.u[j], ua.u[j], 0x05040100u);
                    VtD[nxt][gv * 256 + (((d0v + 2 * j + 1) * 4 + prv) ^ (gv << 2))] =
                        __builtin_amdgcn_perm(ub.u[j], ua.u[j], 0x07060302u);
                }
            }

            // O += P V  (same-wave P; wave-ordered LDS)
#pragma unroll
            for (int c = 0; c < 2; ++c) {
                short8 pa = *(const short8*)&Ps[w][c * 4 + lg][li][0];
#pragma unroll
                for (int dt = 0; dt < 4; ++dt) {
                    int g = c * 4 + lg, d = dt * 16 + li;
                    short8 bv = *(const short8*)(&VtD[cur][g * 256 + ((d * 4) ^ (g << 2))]);
                    oacc[dt] = __builtin_amdgcn_mfma_f32_16x16x32_bf16(pa, bv, oacc[dt], 0, 0, 0);
                }
            }
            __syncthreads();   // drains K(t+1) gld16 + V writes; cur reads done
        }

        // epilogue: 1/l for q-row lg*4+r from lane lg*4+r
        float linv[4];
#pragma unroll
        for (int r = 0; r < 4; ++r) linv[r] = 1.0f / __shfl(lsum, lg * 4 + r, 64);
#pragma unroll
        for (int r = 0; r < 4; ++r) {
            int rg = b * Nseq + r0 + w * 16 + lg * 4 + r;
#pragma unroll
            for (int dt = 0; dt < 4; ++dt)
                o[(size_t)rg * Edim + hq * 64 + dt * 16 + li] =
                    f2bf_u(oacc[dt][r] * linv[r]);
        }
        // loop's final __syncthreads ordered all LDS reads before next half
    }
}

// ---------------- launch ------------------------------------------------------
extern "C" void kernel_launch(void* const* d_in, const int* in_sizes, int n_in,
                              void* d_out, int out_size, void* d_ws, size_t ws_size,
                              hipStream_t stream) {
    const float* x  = (const float*)d_in[0];
    const float* Wq = (const float*)d_in[1];
    const float* Wk = (const float*)d_in[2];
    const float* Wv = (const float*)d_in[3];
    const float* Wo = (const float*)d_in[4];

    ushort* ws    = (ushort*)d_ws;
    ushort* xb    = ws;                          // 4096x1024
    ushort* WqkvT = xb + (size_t)ROWS * Edim;    // 1536x1024 (rows: WqT|WkT|WvT)
    ushort* WoT   = WqkvT + (size_t)QKVW * Edim; // 1024x1024
    ushort* qkv   = WoT + (size_t)Edim * Edim;   // 4096x1536 bf16
    ushort* at    = qkv + (size_t)ROWS * QKVW;   // 4096x1024 bf16

    castx<<<ROWS * Edim / (256 * 8), 256, 0, stream>>>(x, xb);
    tcastAll<<<2560, 256, 0, stream>>>(Wq, Wk, Wv, Wo, WqkvT, WoT);

    gemm_bt<1><<<dim3(QKVW / 64, ROWS / 128), 256, 0, stream>>>(
        xb, WqkvT, qkv, ROWS, QKVW, Edim);

    attn_mfma<<<dim3(Nseq / 128, HQ, Bsz), 256, 0, stream>>>(qkv, at);

    gemm_bt<0><<<dim3(Edim / 64, ROWS / 128), 256, 0, stream>>>(
        at, WoT, d_out, ROWS, Edim, Edim);
}